// Round 1
// baseline (2017.373 us; speedup 1.0000x reference)
//
#include <hip/hip_runtime.h>
#include <math.h>

#define ROW_D 1024   // INV + 3*M
#define INV_D 256
#define K_D   64
#define H_D   512

// ---------------------------------------------------------------------------
// Kernel 1: gate path.  gate = sigmoid( silu(invn @ g_w1 + b1) @ g_w2 + b2 )
// invn = (inv - mean_inv)/std_inv.  Stores gate (fp32) into out[n*64+k];
// chi_kernel later multiplies in place (same stream => ordered).
// 256 threads, 64 atoms/block, grid = N/64.
// ---------------------------------------------------------------------------
__global__ __launch_bounds__(256) void gate_kernel(
    const float* __restrict__ emb,
    const float* __restrict__ mean_inv,
    const float* __restrict__ std_inv,
    const float* __restrict__ g_w1,
    const float* __restrict__ g_b1,
    const float* __restrict__ g_w2,
    const float* __restrict__ g_b2,
    float* __restrict__ out)
{
    __shared__ __align__(16) float a_s[64][36];      // 64 atoms x 32-m chunk (pad 36: 2-way max)
    __shared__ __align__(16) union {
        float w1[32][132];                           // 32 m x 128 h   (GEMM1)
        float w2[64][68];                            // 64 h x 64 k    (GEMM2)
    } w_s;
    __shared__ __align__(16) float hact[64][132];    // 64 atoms x 128 h (silu acts)

    const int tid = threadIdx.x;
    const int tx = tid & 15;         // 16 col-groups
    const int ty = tid >> 4;         // 16 row-groups (4 atoms each)
    const long n0 = (long)blockIdx.x * 64;

    float acc2[4][4];                // atoms ty*4+r, k = tx*4+c, summed over all 512 h
#pragma unroll
    for (int r = 0; r < 4; ++r)
#pragma unroll
        for (int c = 0; c < 4; ++c) acc2[r][c] = 0.f;

    for (int hc = 0; hc < 4; ++hc) {                 // 4 chunks of 128 h
        float acc1[4][8];                            // atoms ty*4+r, h = tx*8+c
#pragma unroll
        for (int r = 0; r < 4; ++r)
#pragma unroll
            for (int c = 0; c < 8; ++c) acc1[r][c] = 0.f;

        for (int mb = 0; mb < 8; ++mb) {             // 8 chunks of 32 m
            __syncthreads();                         // protect a_s/w_s from prior readers
            // stage A: 64 atoms x 32 m = 512 float4
#pragma unroll
            for (int i = 0; i < 2; ++i) {
                const int idx4 = tid + i * 256;
                const int atom = idx4 >> 3;
                const int m4 = (idx4 & 7) << 2;
                const float4 v  = *(const float4*)(emb + (n0 + atom) * ROW_D + mb * 32 + m4);
                const float4 mu = *(const float4*)(mean_inv + mb * 32 + m4);
                const float4 sd = *(const float4*)(std_inv + mb * 32 + m4);
                float4 o;
                o.x = (v.x - mu.x) / sd.x;
                o.y = (v.y - mu.y) / sd.y;
                o.z = (v.z - mu.z) / sd.z;
                o.w = (v.w - mu.w) / sd.w;
                *(float4*)&a_s[atom][m4] = o;
            }
            // stage B: 32 m x 128 h = 1024 float4
#pragma unroll
            for (int i = 0; i < 4; ++i) {
                const int idx4 = tid + i * 256;
                const int row = idx4 >> 5;
                const int c4 = (idx4 & 31) << 2;
                *(float4*)&w_s.w1[row][c4] =
                    *(const float4*)(g_w1 + (mb * 32 + row) * H_D + hc * 128 + c4);
            }
            __syncthreads();
#pragma unroll 8
            for (int m = 0; m < 32; ++m) {
                float a[4];
#pragma unroll
                for (int r = 0; r < 4; ++r) a[r] = a_s[ty * 4 + r][m];
                const float4 b0 = *(const float4*)&w_s.w1[m][tx * 8];
                const float4 b1 = *(const float4*)&w_s.w1[m][tx * 8 + 4];
                const float b[8] = {b0.x, b0.y, b0.z, b0.w, b1.x, b1.y, b1.z, b1.w};
#pragma unroll
                for (int r = 0; r < 4; ++r)
#pragma unroll
                    for (int c = 0; c < 8; ++c) acc1[r][c] += a[r] * b[c];
            }
        }
        __syncthreads();                             // prior GEMM2/GEMM1 readers done
        // silu -> hact
#pragma unroll
        for (int r = 0; r < 4; ++r)
#pragma unroll
            for (int c = 0; c < 8; ++c) {
                const int h = tx * 8 + c;
                const float v = acc1[r][c] + g_b1[hc * 128 + h];
                hact[ty * 4 + r][h] = v / (1.f + __expf(-v));
            }
        for (int hs = 0; hs < 2; ++hs) {             // 2 chunks of 64 h
            __syncthreads();                         // protect w_s union restage
#pragma unroll
            for (int i = 0; i < 4; ++i) {
                const int idx4 = tid + i * 256;
                const int row = idx4 >> 4;
                const int c4 = (idx4 & 15) << 2;
                *(float4*)&w_s.w2[row][c4] =
                    *(const float4*)(g_w2 + (hc * 128 + hs * 64 + row) * K_D + c4);
            }
            __syncthreads();                         // w2 + hact visible
#pragma unroll 8
            for (int h = 0; h < 64; ++h) {
                float a[4];
#pragma unroll
                for (int r = 0; r < 4; ++r) a[r] = hact[ty * 4 + r][hs * 64 + h];
                const float4 b = *(const float4*)&w_s.w2[h][tx * 4];
#pragma unroll
                for (int r = 0; r < 4; ++r) {
                    acc2[r][0] += a[r] * b.x;
                    acc2[r][1] += a[r] * b.y;
                    acc2[r][2] += a[r] * b.z;
                    acc2[r][3] += a[r] * b.w;
                }
            }
        }
    }
    const float4 b2 = *(const float4*)(g_b2 + tx * 4);
#pragma unroll
    for (int r = 0; r < 4; ++r) {
        float4 o;
        o.x = 1.f / (1.f + __expf(-(acc2[r][0] + b2.x)));
        o.y = 1.f / (1.f + __expf(-(acc2[r][1] + b2.y)));
        o.z = 1.f / (1.f + __expf(-(acc2[r][2] + b2.z)));
        o.w = 1.f / (1.f + __expf(-(acc2[r][3] + b2.w)));
        *(float4*)(out + (n0 + ty * 4 + r) * K_D + tx * 4) = o;
    }
}

// ---------------------------------------------------------------------------
// Kernel 2: chi path.  eq-RMSnorm -> x0/x1/x2 (one GEMM (atom,i)x(t,k)) ->
// y1/y2 -> cross -> dot -> LayerNorm -> multiply gate already in out.
// 256 threads, 16 atoms/block, grid = N/16.
// Thread map GEMM: tx = 12-col group, ty = atom.  Stage2: tx = u-sub, ty = atom.
// ---------------------------------------------------------------------------
__global__ __launch_bounds__(256) void chi_kernel(
    const float* __restrict__ emb,
    const float* __restrict__ rms_gamma,
    const float* __restrict__ W0,
    const float* __restrict__ W1,
    const float* __restrict__ W2,
    const float* __restrict__ w_cross,
    const float* __restrict__ w_dot,
    const float* __restrict__ ln_w,
    const float* __restrict__ ln_b,
    float* __restrict__ out)
{
    __shared__ __align__(16) union {
        struct {
            float a[16][97];     // atom x (32 m * 3 i), scaled eq (gamma/rms/16 folded)
            float w[32][196];    // m x (t*64+k), [W0|W1|W2]
        } g;
        float x[16][577];        // atom x (t*192 + k*3 + i)  -- aliases GEMM buffers
    } U;
    __shared__ float wc_s[64][33];   // u x 32-v chunk
    __shared__ float wd_s[64][33];
    __shared__ float red_s[16][17];
    __shared__ float rms_s[16];      // 1/(rms*16)  (s_lin folded)
    __shared__ float chi_s[16][68];

    const int tid = threadIdx.x;
    const int tx = tid & 15;
    const int ty = tid >> 4;
    const long n0 = (long)blockIdx.x * 16;

    // ---- RMS prepass: atom = ty, each tx sums 48 floats of eq^2
    {
        const float* p = emb + (n0 + ty) * ROW_D + INV_D + tx * 48;
        float s = 0.f;
#pragma unroll
        for (int i = 0; i < 12; ++i) {
            const float4 v = *(const float4*)(p + i * 4);
            s += v.x * v.x + v.y * v.y + v.z * v.z + v.w * v.w;
        }
        red_s[ty][tx] = s;
    }
    __syncthreads();
    if (tx == 0) {
        float t = 0.f;
#pragma unroll
        for (int i = 0; i < 16; ++i) t += red_s[ty][i];
        const float rms = sqrtf(t * (1.f / 256.f) + 1e-6f);
        rms_s[ty] = 1.f / (rms * 16.f);
    }
    __syncthreads();

    // ---- GEMM: acc[i][c] = x_t[atom][k][i], col = tx*12+c = t*64+k
    float acc[3][12];
#pragma unroll
    for (int i = 0; i < 3; ++i)
#pragma unroll
        for (int c = 0; c < 12; ++c) acc[i][c] = 0.f;

    for (int mb = 0; mb < 8; ++mb) {
        __syncthreads();
        // stage A: 16 atoms x 96 floats (32 m * 3 i), scaled
#pragma unroll
        for (int i = 0; i < 6; ++i) {
            const int idx = tid + i * 256;
            const int atom = idx / 96;
            const int o = idx - atom * 96;
            U.g.a[atom][o] = emb[(n0 + atom) * ROW_D + INV_D + mb * 96 + o]
                           * rms_gamma[mb * 32 + o / 3] * rms_s[atom];
        }
        // stage B: 32 m x 192 cols = 1536 float4
#pragma unroll
        for (int i = 0; i < 6; ++i) {
            const int idx4 = tid + i * 256;
            const int row = idx4 / 48;
            const int c4 = idx4 - row * 48;
            const int tsel = c4 >> 4;
            const int k4 = (c4 & 15) << 2;
            const float* Wt = (tsel == 0) ? W0 : ((tsel == 1) ? W1 : W2);
            *(float4*)&U.g.w[row][tsel * 64 + k4] =
                *(const float4*)(Wt + (mb * 32 + row) * K_D + k4);
        }
        __syncthreads();
#pragma unroll 8
        for (int m = 0; m < 32; ++m) {
            const float a0 = U.g.a[ty][m * 3 + 0];
            const float a1 = U.g.a[ty][m * 3 + 1];
            const float a2 = U.g.a[ty][m * 3 + 2];
            const float4 b0 = *(const float4*)&U.g.w[m][tx * 12];
            const float4 b1 = *(const float4*)&U.g.w[m][tx * 12 + 4];
            const float4 b2 = *(const float4*)&U.g.w[m][tx * 12 + 8];
            const float b[12] = {b0.x, b0.y, b0.z, b0.w, b1.x, b1.y, b1.z, b1.w,
                                 b2.x, b2.y, b2.z, b2.w};
#pragma unroll
            for (int c = 0; c < 12; ++c) {
                acc[0][c] += a0 * b[c];
                acc[1][c] += a1 * b[c];
                acc[2][c] += a2 * b[c];
            }
        }
    }

    // ---- write x to LDS (aliases a/w: barrier first)
    __syncthreads();
#pragma unroll
    for (int c = 0; c < 12; ++c) {
        const int col = tx * 12 + c;
        const int tsel = col >> 6;
        const int k = col & 63;
#pragma unroll
        for (int i = 0; i < 3; ++i)
            U.x[ty][tsel * 192 + k * 3 + i] = acc[i][c];
    }
    __syncthreads();

    // ---- stage2: atom = ty, u = tx + 16*s
    float y1[4][3], y2[4][3];
#pragma unroll
    for (int s = 0; s < 4; ++s)
#pragma unroll
        for (int j = 0; j < 3; ++j) { y1[s][j] = 0.f; y2[s][j] = 0.f; }

    for (int vb = 0; vb < 2; ++vb) {
        __syncthreads();                 // protect wc_s/wd_s restage
#pragma unroll
        for (int i = 0; i < 8; ++i) {
            const int idx = tid + i * 256;
            const int u = idx >> 5;
            const int v = idx & 31;
            wc_s[u][v] = w_cross[u * 64 + vb * 32 + v];
            wd_s[u][v] = w_dot[u * 64 + vb * 32 + v];
        }
        __syncthreads();
#pragma unroll 4
        for (int v = 0; v < 32; ++v) {
            const int vg = vb * 32 + v;
            float x1j[3], x2j[3];
#pragma unroll
            for (int j = 0; j < 3; ++j) {
                x1j[j] = U.x[ty][192 + vg * 3 + j];
                x2j[j] = U.x[ty][384 + vg * 3 + j];
            }
#pragma unroll
            for (int s = 0; s < 4; ++s) {
                const float wc = wc_s[tx + 16 * s][v];
                const float wd = wd_s[tx + 16 * s][v];
#pragma unroll
                for (int j = 0; j < 3; ++j) {
                    y1[s][j] += wc * x1j[j];
                    y2[s][j] += wd * x2j[j];
                }
            }
        }
    }

    // ---- cross, dot, chi
    const float CHI_SCALE = 1.0f / sqrtf(24576.0f);   // 1/(sqrt(2K)*sqrt(3K))
#pragma unroll
    for (int s = 0; s < 4; ++s) {
        const int u = tx + 16 * s;
        float x0j[3];
#pragma unroll
        for (int j = 0; j < 3; ++j) x0j[j] = U.x[ty][u * 3 + j];
        const float c0 = x0j[1] * y1[s][2] - x0j[2] * y1[s][1];
        const float c1 = x0j[2] * y1[s][0] - x0j[0] * y1[s][2];
        const float c2 = x0j[0] * y1[s][1] - x0j[1] * y1[s][0];
        chi_s[ty][u] = (c0 * y2[s][0] + c1 * y2[s][1] + c2 * y2[s][2]) * CHI_SCALE;
    }
    __syncthreads();

    // ---- LayerNorm over u, multiply gate (already in out), store final
    float mu = 0.f;
#pragma unroll 16
    for (int u = 0; u < 64; ++u) mu += chi_s[ty][u];
    mu *= (1.f / 64.f);
    float var = 0.f;
#pragma unroll 16
    for (int u = 0; u < 64; ++u) { const float d = chi_s[ty][u] - mu; var += d * d; }
    var *= (1.f / 64.f);
    const float isd = rsqrtf(var + 1e-5f);
#pragma unroll
    for (int s = 0; s < 4; ++s) {
        const int u = tx + 16 * s;
        const float val = (chi_s[ty][u] - mu) * isd * ln_w[u] + ln_b[u];
        const long o = (n0 + ty) * K_D + u;
        out[o] = out[o] * val;
    }
}

extern "C" void kernel_launch(void* const* d_in, const int* in_sizes, int n_in,
                              void* d_out, int out_size, void* d_ws, size_t ws_size,
                              hipStream_t stream)
{
    const float* emb       = (const float*)d_in[0];
    const float* mean_inv  = (const float*)d_in[1];
    const float* std_inv   = (const float*)d_in[2];
    const float* rms_gamma = (const float*)d_in[3];
    const float* W0        = (const float*)d_in[4];
    const float* W1        = (const float*)d_in[5];
    const float* W2        = (const float*)d_in[6];
    const float* w_cross   = (const float*)d_in[7];
    const float* w_dot     = (const float*)d_in[8];
    const float* ln_w      = (const float*)d_in[9];
    const float* ln_b      = (const float*)d_in[10];
    const float* g_w1      = (const float*)d_in[11];
    const float* g_b1      = (const float*)d_in[12];
    const float* g_w2      = (const float*)d_in[13];
    const float* g_b2      = (const float*)d_in[14];
    float* out = (float*)d_out;

    const int N = in_sizes[0] / ROW_D;   // 131072

    gate_kernel<<<N / 64, 256, 0, stream>>>(emb, mean_inv, std_inv,
                                            g_w1, g_b1, g_w2, g_b2, out);
    chi_kernel<<<N / 16, 256, 0, stream>>>(emb, rms_gamma, W0, W1, W2,
                                           w_cross, w_dot, ln_w, ln_b, out);
}

// Round 2
// 1038.521 us; speedup vs baseline: 1.9425x; 1.9425x over previous
//
#include <hip/hip_runtime.h>
#include <math.h>

#define ROW_D 1024   // INV + 3*M
#define INV_D 256

typedef short bf16x8 __attribute__((ext_vector_type(8)));
typedef float f32x4 __attribute__((ext_vector_type(4)));

#define MFMA16(a,b,c) __builtin_amdgcn_mfma_f32_16x16x32_bf16((a),(b),(c),0,0,0)

__device__ __forceinline__ unsigned short f2bf(float f) {
    union { float f; unsigned int u; } x; x.f = f;
    return (unsigned short)((x.u + 0x7FFFu + ((x.u >> 16) & 1u)) >> 16);  // RNE
}
__device__ __forceinline__ float bf2f(unsigned short h) {
    union { unsigned int u; float f; } x; x.u = ((unsigned int)h) << 16;
    return x.f;
}

// ---------------------------------------------------------------------------
// Prep: bf16 weight repack into d_ws (runs every launch; ~3 us).
//  W1t[h][m] = bf16(g_w1[m][h] / std[m])            (512x256)  norm folded
//  W2t[k][h] = bf16(g_w2[h][k])                     (64x512)
//  Wcat[t*64+k][m] = bf16(W_t[m][k] * gamma[m]/16)  (192x256)  gamma,s_lin folded
//  wcb[u][v] = bf16(w_cross[u][v]), wdb likewise    (64x64)    (= B^T layout)
//  b1p[h] = g_b1[h] - sum_m mean[m]/std[m]*g_w1[m][h]
// ---------------------------------------------------------------------------
__global__ void prep_kernel(
    const float* __restrict__ g_w1, const float* __restrict__ mean_inv,
    const float* __restrict__ std_inv, const float* __restrict__ g_w2,
    const float* __restrict__ W0, const float* __restrict__ W1,
    const float* __restrict__ W2, const float* __restrict__ rms_gamma,
    const float* __restrict__ w_cross, const float* __restrict__ w_dot,
    const float* __restrict__ g_b1,
    unsigned short* __restrict__ W1t, unsigned short* __restrict__ W2t,
    unsigned short* __restrict__ Wcat, unsigned short* __restrict__ wcb,
    unsigned short* __restrict__ wdb, float* __restrict__ b1p)
{
    const int nth = gridDim.x * 256;
    for (int idx = blockIdx.x * 256 + threadIdx.x; idx < 221696; idx += nth) {
        if (idx < 131072) {
            int h = idx >> 8, m = idx & 255;
            W1t[idx] = f2bf(g_w1[m * 512 + h] / std_inv[m]);
        } else if (idx < 163840) {
            int t = idx - 131072; int k = t >> 9, h = t & 511;
            W2t[t] = f2bf(g_w2[h * 64 + k]);
        } else if (idx < 212992) {
            int t = idx - 163840; int r = t >> 8, m = t & 255;
            int tt = r >> 6, k = r & 63;
            const float* Wt = (tt == 0) ? W0 : ((tt == 1) ? W1 : W2);
            Wcat[t] = f2bf(Wt[m * 64 + k] * rms_gamma[m] * 0.0625f);
        } else if (idx < 217088) {
            int t = idx - 212992; wcb[t] = f2bf(w_cross[t]);
        } else if (idx < 221184) {
            int t = idx - 217088; wdb[t] = f2bf(w_dot[t]);
        } else {
            int h = idx - 221184;
            float s = 0.f;
            for (int m = 0; m < 256; ++m)
                s += mean_inv[m] / std_inv[m] * g_w1[m * 512 + h];
            b1p[h] = g_b1[h] - s;
        }
    }
}

// ---------------------------------------------------------------------------
// Gate: sigmoid( silu(inv @ W1' + b1') @ W2 + b2 ) -> out (fp32 gate)
// 128 atoms/block, 256 thr (4 waves). hc: 8 chunks of 64 h; kb: 4 chunks of 64 m.
// Wave w owns tile-rows {2w,2w+1} (atoms [32w,32w+32)) x 4 tile-cols.
// LDS 46080 B -> 2 blocks/CU. frag-reads:MFMA = 6:8 per kstep.
// ---------------------------------------------------------------------------
__global__ __launch_bounds__(256, 2) void gate_kernel(
    const float* __restrict__ emb,
    const unsigned short* __restrict__ W1t,   // [512][256] bf16
    const unsigned short* __restrict__ W2t,   // [64][512]  bf16
    const float* __restrict__ b1p,            // [512]
    const float* __restrict__ g_b2,           // [64]
    float* __restrict__ out)
{
    __shared__ __align__(16) char smem[46080];
    unsigned short* As   = (unsigned short*)smem;            // [128][72] 18432
    unsigned short* B1s  = (unsigned short*)(smem + 18432);  // [64][72]  9216 (alias B2s)
    unsigned short* B2s  = B1s;
    unsigned short* acts = (unsigned short*)(smem + 27648);  // [128][72] 18432

    const int tid = threadIdx.x;
    const int wv = tid >> 6, ln = tid & 63;
    const int lr = ln & 15, lq = ln >> 4;
    const long n0 = (long)blockIdx.x * 128;

    f32x4 acc2[2][4];
#pragma unroll
    for (int r = 0; r < 2; ++r)
#pragma unroll
        for (int c = 0; c < 4; ++c) acc2[r][c] = (f32x4){0.f, 0.f, 0.f, 0.f};

    for (int hc = 0; hc < 8; ++hc) {
        f32x4 acc1[2][4];
#pragma unroll
        for (int r = 0; r < 2; ++r)
#pragma unroll
            for (int c = 0; c < 4; ++c) acc1[r][c] = (f32x4){0.f, 0.f, 0.f, 0.f};

        for (int kb = 0; kb < 4; ++kb) {
            __syncthreads();   // prior readers of As/B1s(B2s) done
            // stage A: 128 atoms x 64 m fp32 -> bf16
#pragma unroll
            for (int i = 0; i < 8; ++i) {
                int idx = tid + i * 256;
                int atom = idx >> 4;
                int c4 = (idx & 15) << 2;
                float4 v = *(const float4*)(emb + (n0 + atom) * ROW_D + kb * 64 + c4);
                ushort4 h;
                h.x = f2bf(v.x); h.y = f2bf(v.y); h.z = f2bf(v.z); h.w = f2bf(v.w);
                *(ushort4*)&As[atom * 72 + c4] = h;
            }
            // stage B1: 64 h x 64 m bf16 (16B copies)
#pragma unroll
            for (int i = 0; i < 2; ++i) {
                int idx = tid + i * 256;
                int row = idx >> 3, c8 = (idx & 7) << 3;
                *(uint4*)&B1s[row * 72 + c8] =
                    *(const uint4*)(W1t + (hc * 64 + row) * 256 + kb * 64 + c8);
            }
            __syncthreads();
#pragma unroll
            for (int ks = 0; ks < 2; ++ks) {
                bf16x8 af[2];
#pragma unroll
                for (int r = 0; r < 2; ++r)
                    af[r] = *(const bf16x8*)&As[((wv * 2 + r) * 16 + lr) * 72 + ks * 32 + lq * 8];
#pragma unroll
                for (int c = 0; c < 4; ++c) {
                    bf16x8 bf = *(const bf16x8*)&B1s[(c * 16 + lr) * 72 + ks * 32 + lq * 8];
                    acc1[0][c] = MFMA16(af[0], bf, acc1[0][c]);
                    acc1[1][c] = MFMA16(af[1], bf, acc1[1][c]);
                }
            }
        }
        __syncthreads();   // GEMM1 reads done -> acts/B2s writable
        // silu -> acts (wave-local rows)
#pragma unroll
        for (int r = 0; r < 2; ++r)
#pragma unroll
            for (int c = 0; c < 4; ++c) {
                int hl = c * 16 + lr;
                float b = b1p[hc * 64 + hl];
#pragma unroll
                for (int g = 0; g < 4; ++g) {
                    int atom = (wv * 2 + r) * 16 + lq * 4 + g;
                    float v = acc1[r][c][g] + b;
                    acts[atom * 72 + hl] = f2bf(v / (1.f + __expf(-v)));
                }
            }
        // stage B2: 64 k x 64 h
#pragma unroll
        for (int i = 0; i < 2; ++i) {
            int idx = tid + i * 256;
            int row = idx >> 3, c8 = (idx & 7) << 3;
            *(uint4*)&B2s[row * 72 + c8] =
                *(const uint4*)(W2t + row * 512 + hc * 64 + c8);
        }
        __syncthreads();
#pragma unroll
        for (int ks = 0; ks < 2; ++ks) {
            bf16x8 af[2];
#pragma unroll
            for (int r = 0; r < 2; ++r)
                af[r] = *(const bf16x8*)&acts[((wv * 2 + r) * 16 + lr) * 72 + ks * 32 + lq * 8];
#pragma unroll
            for (int c = 0; c < 4; ++c) {
                bf16x8 bf = *(const bf16x8*)&B2s[(c * 16 + lr) * 72 + ks * 32 + lq * 8];
                acc2[0][c] = MFMA16(af[0], bf, acc2[0][c]);
                acc2[1][c] = MFMA16(af[1], bf, acc2[1][c]);
            }
        }
    }
#pragma unroll
    for (int r = 0; r < 2; ++r)
#pragma unroll
        for (int c = 0; c < 4; ++c) {
            int k = c * 16 + lr;
            float b2v = g_b2[k];
#pragma unroll
            for (int g = 0; g < 4; ++g) {
                int atom = (wv * 2 + r) * 16 + lq * 4 + g;
                float v = acc2[r][c][g] + b2v;
                out[(n0 + atom) * 64 + k] = 1.f / (1.f + __expf(-v));
            }
        }
}

// ---------------------------------------------------------------------------
// Chi: rms(eq) -> x0/x1/x2 via MFMA [(i,atom)=96 rows x (t,k)=192 cols, K=256]
//      -> y1/y2 via MFMA [(atom,j)=96 rows x u=64 cols, K=64, B-frags from global]
//      -> cross/dot -> LN -> out *= (in-place with gate).
// 32 atoms/block, 256 thr. LDS union 41472 + x0 12544 + chi 8448 + rms = 62592.
// ---------------------------------------------------------------------------
__global__ __launch_bounds__(256, 2) void chi_kernel(
    const float* __restrict__ emb,
    const unsigned short* __restrict__ Wcat,  // [192][256] bf16
    const unsigned short* __restrict__ wcb,   // [64][64] bf16
    const unsigned short* __restrict__ wdb,   // [64][64] bf16
    const float* __restrict__ ln_w,
    const float* __restrict__ ln_b,
    float* __restrict__ out)
{
    __shared__ __align__(16) char smem[62592];
    // phase A (GEMM1):
    unsigned short* Aeq = (unsigned short*)smem;             // [96][72]  13824
    unsigned short* Bw  = (unsigned short*)(smem + 13824);   // [192][72] 27648 (end 41472)
    // phase B (x dump + stage2):  aliases A
    unsigned short* Xl1 = (unsigned short*)smem;             // [96][72] x1 as [(a,j)][v]
    unsigned short* Xl2 = (unsigned short*)(smem + 13824);   // [96][72] x2
    // phase C (y): aliases Xl
    unsigned short* y1l = (unsigned short*)smem;             // [96][72] bf16 [(a,j)][u]
    unsigned short* y2l = (unsigned short*)(smem + 13824);
    // persistent:
    unsigned short* x0l = (unsigned short*)(smem + 41472);   // [32][196] bf16 [a][k*3+i]
    float* chi_s = (float*)(smem + 54016);                   // [32][66]
    float* rms_s = (float*)(smem + 62464);                   // [32]

    const int tid = threadIdx.x;
    const int wv = tid >> 6, ln = tid & 63;
    const int lr = ln & 15, lq = ln >> 4;
    const int a_t = tid >> 3, st = tid & 7;   // staging/epilogue: 8 thr per atom
    const long n0 = (long)blockIdx.x * 32;

    f32x4 acc[6][3];
#pragma unroll
    for (int tr = 0; tr < 6; ++tr)
#pragma unroll
        for (int c = 0; c < 3; ++c) acc[tr][c] = (f32x4){0.f, 0.f, 0.f, 0.f};
    float sumsq = 0.f;

    for (int kb = 0; kb < 4; ++kb) {
        __syncthreads();
        // stage A: de-interleave eq chunk (64 m x 3 i) + accumulate sum(eq^2)
#pragma unroll
        for (int j = 0; j < 6; ++j) {
            int c = (st + 8 * j) * 4;
            float4 v = *(const float4*)(emb + (n0 + a_t) * ROW_D + INV_D + kb * 192 + c);
            sumsq += v.x * v.x + v.y * v.y + v.z * v.z + v.w * v.w;
            float vv[4] = {v.x, v.y, v.z, v.w};
#pragma unroll
            for (int e = 0; e < 4; ++e) {
                int col = c + e;
                int ml = col / 3;
                int ii = col - ml * 3;
                Aeq[(ii * 32 + a_t) * 72 + ml] = f2bf(vv[e]);
            }
        }
        // stage B: Wcat rows x 64-m chunk
#pragma unroll
        for (int i = 0; i < 6; ++i) {
            int idx = tid + i * 256;
            int row = idx >> 3, c8 = (idx & 7) << 3;
            *(uint4*)&Bw[row * 72 + c8] =
                *(const uint4*)(Wcat + row * 256 + kb * 64 + c8);
        }
        __syncthreads();
#pragma unroll
        for (int ks = 0; ks < 2; ++ks) {
            bf16x8 bfr[3];
#pragma unroll
            for (int c = 0; c < 3; ++c)
                bfr[c] = *(const bf16x8*)&Bw[((wv * 3 + c) * 16 + lr) * 72 + ks * 32 + lq * 8];
#pragma unroll
            for (int tr = 0; tr < 6; ++tr) {
                bf16x8 af = *(const bf16x8*)&Aeq[(tr * 16 + lr) * 72 + ks * 32 + lq * 8];
#pragma unroll
                for (int c = 0; c < 3; ++c)
                    acc[tr][c] = MFMA16(af, bfr[c], acc[tr][c]);
            }
        }
    }
    // rms: reduce 8 threads of each atom
    sumsq += __shfl_xor(sumsq, 1);
    sumsq += __shfl_xor(sumsq, 2);
    sumsq += __shfl_xor(sumsq, 4);
    if (st == 0) rms_s[a_t] = rsqrtf(sumsq * (1.f / 256.f) + 1e-6f);
    __syncthreads();   // rms visible; all GEMM1 reads done -> union writable

    // dump x: acc tile (tr, wv*3+c): rows (i,atom), cols (t,k). 1/rms applied here.
#pragma unroll
    for (int tr = 0; tr < 6; ++tr)
#pragma unroll
        for (int c = 0; c < 3; ++c) {
            int colg = (wv * 3 + c) * 16 + lr;
            int t = colg >> 6, k = colg & 63;
#pragma unroll
            for (int g = 0; g < 4; ++g) {
                int rowg = tr * 16 + lq * 4 + g;
                int ii = rowg >> 5, atom = rowg & 31;
                unsigned short hb = f2bf(acc[tr][c][g] * rms_s[atom]);
                if (t == 0)      x0l[atom * 196 + k * 3 + ii] = hb;
                else if (t == 1) Xl1[(atom * 3 + ii) * 72 + k] = hb;
                else             Xl2[(atom * 3 + ii) * 72 + k] = hb;
            }
        }
    __syncthreads();   // Xl visible to all waves

    // stage 2: wave -> tensor ts=wv&1 (y1:wc / y2:wd), tile-col pair cp=wv>>1
    const int ts = wv & 1, cp = wv >> 1;
    const unsigned short* Xs = ts ? Xl2 : Xl1;
    const unsigned short* Wg = ts ? wdb : wcb;
    f32x4 yacc[6][2];
#pragma unroll
    for (int tr = 0; tr < 6; ++tr)
#pragma unroll
        for (int c = 0; c < 2; ++c) yacc[tr][c] = (f32x4){0.f, 0.f, 0.f, 0.f};
#pragma unroll
    for (int ks = 0; ks < 2; ++ks) {
        bf16x8 bfr[2];
#pragma unroll
        for (int c = 0; c < 2; ++c)
            bfr[c] = *(const bf16x8*)(Wg + ((cp * 2 + c) * 16 + lr) * 64 + ks * 32 + lq * 8);
#pragma unroll
        for (int tr = 0; tr < 6; ++tr) {
            bf16x8 af = *(const bf16x8*)&Xs[(tr * 16 + lr) * 72 + ks * 32 + lq * 8];
#pragma unroll
            for (int c = 0; c < 2; ++c)
                yacc[tr][c] = MFMA16(af, bfr[c], yacc[tr][c]);
        }
    }
    __syncthreads();   // Xl reads done -> y region writable

    unsigned short* Yd = ts ? y2l : y1l;
#pragma unroll
    for (int tr = 0; tr < 6; ++tr)
#pragma unroll
        for (int c = 0; c < 2; ++c) {
            int u = (cp * 2 + c) * 16 + lr;
#pragma unroll
            for (int g = 0; g < 4; ++g) {
                int rowg = tr * 16 + lq * 4 + g;
                Yd[rowg * 72 + u] = f2bf(yacc[tr][c][g]);
            }
        }
    __syncthreads();

    // cross, dot, chi   (thread: atom a_t, u = st + 8q)
    const float CHI_SCALE = 1.0f / sqrtf(24576.0f);   // 1/(sqrt(2K)*sqrt(3K))
#pragma unroll
    for (int q = 0; q < 8; ++q) {
        int u = st + 8 * q;
        float x0a = bf2f(x0l[a_t * 196 + u * 3 + 0]);
        float x0b = bf2f(x0l[a_t * 196 + u * 3 + 1]);
        float x0c = bf2f(x0l[a_t * 196 + u * 3 + 2]);
        float y1a = bf2f(y1l[(a_t * 3 + 0) * 72 + u]);
        float y1b = bf2f(y1l[(a_t * 3 + 1) * 72 + u]);
        float y1c = bf2f(y1l[(a_t * 3 + 2) * 72 + u]);
        float y2a = bf2f(y2l[(a_t * 3 + 0) * 72 + u]);
        float y2b = bf2f(y2l[(a_t * 3 + 1) * 72 + u]);
        float y2c = bf2f(y2l[(a_t * 3 + 2) * 72 + u]);
        float c0 = x0b * y1c - x0c * y1b;
        float c1 = x0c * y1a - x0a * y1c;
        float c2 = x0a * y1b - x0b * y1a;
        chi_s[a_t * 66 + u] = (c0 * y2a + c1 * y2b + c2 * y2c) * CHI_SCALE;
    }
    __syncthreads();

    // LayerNorm over u (8 threads/atom, shfl reduce) + gate multiply
    float s = 0.f;
#pragma unroll
    for (int q = 0; q < 8; ++q) s += chi_s[a_t * 66 + st + 8 * q];
    s += __shfl_xor(s, 1); s += __shfl_xor(s, 2); s += __shfl_xor(s, 4);
    float mu = s * (1.f / 64.f);
    float vv = 0.f;
#pragma unroll
    for (int q = 0; q < 8; ++q) {
        float d = chi_s[a_t * 66 + st + 8 * q] - mu;
        vv += d * d;
    }
    vv += __shfl_xor(vv, 1); vv += __shfl_xor(vv, 2); vv += __shfl_xor(vv, 4);
    float isd = rsqrtf(vv * (1.f / 64.f) + 1e-5f);
#pragma unroll
    for (int q = 0; q < 8; ++q) {
        int u = st + 8 * q;
        float val = (chi_s[a_t * 66 + u] - mu) * isd * ln_w[u] + ln_b[u];
        long o = (n0 + a_t) * 64 + u;
        out[o] = out[o] * val;
    }
}

extern "C" void kernel_launch(void* const* d_in, const int* in_sizes, int n_in,
                              void* d_out, int out_size, void* d_ws, size_t ws_size,
                              hipStream_t stream)
{
    const float* emb       = (const float*)d_in[0];
    const float* mean_inv  = (const float*)d_in[1];
    const float* std_inv   = (const float*)d_in[2];
    const float* rms_gamma = (const float*)d_in[3];
    const float* W0        = (const float*)d_in[4];
    const float* W1        = (const float*)d_in[5];
    const float* W2        = (const float*)d_in[6];
    const float* w_cross   = (const float*)d_in[7];
    const float* w_dot     = (const float*)d_in[8];
    const float* ln_w      = (const float*)d_in[9];
    const float* ln_b      = (const float*)d_in[10];
    const float* g_w1      = (const float*)d_in[11];
    const float* g_b1      = (const float*)d_in[12];
    const float* g_w2      = (const float*)d_in[13];
    const float* g_b2      = (const float*)d_in[14];
    float* out = (float*)d_out;

    char* ws = (char*)d_ws;
    unsigned short* W1t  = (unsigned short*)(ws);            // 512*256*2 = 262144
    unsigned short* W2t  = (unsigned short*)(ws + 262144);   // 64*512*2  = 65536
    unsigned short* Wcat = (unsigned short*)(ws + 327680);   // 192*256*2 = 98304
    unsigned short* wcb  = (unsigned short*)(ws + 425984);   // 64*64*2   = 8192
    unsigned short* wdb  = (unsigned short*)(ws + 434176);   // 8192
    float*          b1p  = (float*)(ws + 442368);            // 512*4     = 2048

    const int N = in_sizes[0] / ROW_D;   // 131072

    prep_kernel<<<128, 256, 0, stream>>>(g_w1, mean_inv, std_inv, g_w2,
                                         W0, W1, W2, rms_gamma, w_cross, w_dot,
                                         g_b1, W1t, W2t, Wcat, wcb, wdb, b1p);
    gate_kernel<<<N / 128, 256, 0, stream>>>(emb, W1t, W2t, b1p, g_b2, out);
    chi_kernel<<<N / 32, 256, 0, stream>>>(emb, Wcat, wcb, wdb, ln_w, ln_b, out);
}